// Round 10
// baseline (243.587 us; speedup 1.0000x reference)
//
#include <hip/hip_runtime.h>
#include <cstdint>

// MHA fwd: B=4, S=2048, D=1024, H=16, HD=64. fp32 in/out.
// Round 10: (1) attn v7 = V read DIRECT from global (L2-resident, XCD-pinned heads;
// drops V staging + 8 ds_read/iter) + K TRIPLE-buffered with ONE barrier/iter.
// (2) all pre-passes fused into one `prep` launch. GEMMs = round-9 m97 structure.

typedef __bf16 bf16x8 __attribute__((ext_vector_type(8)));
typedef __bf16 bf16x4v __attribute__((ext_vector_type(4)));
typedef float f32x4 __attribute__((ext_vector_type(4)));
typedef unsigned u32x2 __attribute__((ext_vector_type(2)));
typedef unsigned u32x4 __attribute__((ext_vector_type(4)));

#define DEV __device__ __forceinline__

#if __has_builtin(__builtin_amdgcn_exp2f)
#define EXP2(x) __builtin_amdgcn_exp2f(x)
#else
#define EXP2(x) exp2f(x)
#endif

DEV __bf16 f2bf(float f) { return (__bf16)f; }

DEV void gload16(const void* g, void* l) {
  __builtin_amdgcn_global_load_lds(
      (const __attribute__((address_space(1))) unsigned int*)(uintptr_t)g,
      (__attribute__((address_space(3))) unsigned int*)(uintptr_t)l,
      16, 0, 0);
}

#define MFMA16(a, b, c) __builtin_amdgcn_mfma_f32_16x16x32_bf16((a), (b), (c), 0, 0, 0)

// ------------------------------------------------------- fused pre-pass kernel
// blocks [0,2048): x fp32 -> bf16 (grid-stride float4)
// blocks [2048,6144): W transpose+convert: which = (blk-2048)>>10
// block 6144: mask bit-pack + qkv bias pack
__global__ __launch_bounds__(256) void prep(const float* __restrict__ x,
                                            bf16x4v* __restrict__ xb,
                                            const float* __restrict__ Wq,
                                            const float* __restrict__ Wk,
                                            const float* __restrict__ Wv,
                                            const float* __restrict__ Wo,
                                            __bf16* __restrict__ wtall, float qs,
                                            const unsigned char* __restrict__ mask,
                                            unsigned* __restrict__ pm,
                                            const float* __restrict__ bq,
                                            const float* __restrict__ bk,
                                            const float* __restrict__ bv,
                                            float* __restrict__ pb) {
  const int blk = blockIdx.x, t = threadIdx.x;
  if (blk < 2048) {
    const float4* in = (const float4*)x;
    int i = blk * 256 + t;
    for (; i < 2097152; i += 2048 * 256) {
      float4 v = in[i];
      bf16x4v o = { f2bf(v.x), f2bf(v.y), f2bf(v.z), f2bf(v.w) };
      xb[i] = o;
    }
  } else if (blk < 6144) {
    __shared__ float tile[32][33];
    const int idx = blk - 2048;
    const int which = idx >> 10, tb = idx & 1023;
    const float* src = which == 0 ? Wq : which == 1 ? Wk : which == 2 ? Wv : Wo;
    const float scale = (which == 0) ? qs : 1.0f;
    __bf16* dst = wtall + (size_t)which * 1024 * 1024;
    const int tx = t & 31, ty = t >> 5;
    const int x0 = (tb & 31) * 32, y0 = (tb >> 5) * 32;
#pragma unroll
    for (int j = 0; j < 4; ++j)
      tile[ty + j * 8][tx] = src[(size_t)(y0 + ty + j * 8) * 1024 + x0 + tx];
    __syncthreads();
#pragma unroll
    for (int j = 0; j < 4; ++j)
      dst[(size_t)(x0 + ty + j * 8) * 1024 + y0 + tx] = f2bf(tile[tx][ty + j * 8] * scale);
  } else {
    // mask: pm[b*64 + tile*2 + half] bit j = mask[b][tile*64 + half*32 + j]
    int b = t >> 6, tl = (t >> 1) & 31, half = t & 1;
    unsigned bits = 0;
    for (int j = 0; j < 32; ++j)
      if (mask[b * 2048 + tl * 64 + half * 32 + j]) bits |= (1u << j);
    pm[b * 64 + tl * 2 + half] = bits;
    // bias: packed 3072 (q pre-scaled)
    for (int i = t; i < 3072; i += 256) {
      float v = (i < 1024) ? bq[i] * qs : (i < 2048) ? bk[i - 1024] : bv[i - 2048];
      pb[i] = v;
    }
  }
}

// --------------------------------------------------------------- 128x128 GEMM
// m97 structure: single-buffered 32KB LDS, stage -> __syncthreads -> MFMA ->
// __syncthreads; XOR chunk-swizzled staging/reads; 4 blocks/CU; m-fast XCD grid.
// mode 2: fp32 row-major out to o0 (N=1024)
// mode 3: fused QKV (N=3072): seg 0 -> q head-split, 1 -> k head-split,
//         2 -> v transposed (bh,hd,s) with in-tile key-slot permutation.
__global__ __launch_bounds__(256, 4) void gemm128(const __bf16* __restrict__ A,
                                                  const __bf16* __restrict__ Bt,
                                                  const float* __restrict__ bias,
                                                  void* __restrict__ o0, void* __restrict__ o1,
                                                  void* __restrict__ o2, int mode) {
  constexpr int K = 1024;
  __shared__ alignas(16) __bf16 S[16384];
  __bf16* As_ = S;
  __bf16* Bs_ = S + 8192;
  const int t = threadIdx.x;
  const int lane = t & 63, w = t >> 6;
  const int g = lane >> 4, c = lane & 15;
  const int sw = c & 7;
  const int wm = w & 1, wn = w >> 1;
  const int bid = blockIdx.x;
  const int j = bid >> 3;
  const int m0 = (((bid & 7) << 3) + (j & 7)) << 7;
  const int n0 = (j >> 3) << 7;

  float bb4[4];
#pragma unroll
  for (int jj = 0; jj < 4; ++jj) bb4[jj] = bias[n0 + wn * 64 + jj * 16 + c];

  f32x4 acc[4][4];
#pragma unroll
  for (int i = 0; i < 4; ++i)
#pragma unroll
    for (int jj = 0; jj < 4; ++jj) acc[i][jj] = f32x4{0.f, 0.f, 0.f, 0.f};

#pragma unroll 1
  for (int kt = 0; kt < 16; ++kt) {
    const int k0 = kt << 6;
#pragma unroll
    for (int i = 0; i < 4; ++i) {
      int slot = i * 256 + t;
      int row = slot >> 3;
      int gch = (slot & 7) ^ (row & 7);
      gload16(&A[(size_t)(m0 + row) * K + k0 + gch * 8], &As_[slot * 8]);
      gload16(&Bt[(size_t)(n0 + row) * K + k0 + gch * 8], &Bs_[slot * 8]);
    }
    __syncthreads();
#pragma unroll
    for (int kk = 0; kk < 2; ++kk) {
      bf16x8 af[4], bfr[4];
#pragma unroll
      for (int i = 0; i < 4; ++i) {
        af[i]  = *(const bf16x8*)&As_[(wm * 64 + i * 16 + c) * 64 + (((kk * 4 + g) ^ sw) << 3)];
        bfr[i] = *(const bf16x8*)&Bs_[(wn * 64 + i * 16 + c) * 64 + (((kk * 4 + g) ^ sw) << 3)];
      }
#pragma unroll
      for (int i = 0; i < 4; ++i)
#pragma unroll
        for (int jj = 0; jj < 4; ++jj)
          acc[i][jj] = MFMA16(af[i], bfr[jj], acc[i][jj]);
    }
    __syncthreads();
  }

  const int bidx = m0 >> 11;
  const int s0g = m0 & 2047;

  if (mode == 2) {
#pragma unroll
    for (int i = 0; i < 4; ++i) {
      const int rowb = m0 + wm * 64 + i * 16 + g * 4;
#pragma unroll
      for (int jj = 0; jj < 4; ++jj) {
        const int col = n0 + wn * 64 + jj * 16 + c;
#pragma unroll
        for (int r = 0; r < 4; ++r)
          ((float*)o0)[(size_t)(rowb + r) * 1024 + col] = acc[i][jj][r] + bb4[jj];
      }
    }
    return;
  }

  const int seg = n0 >> 10;
  const int hb = (n0 & 1023) >> 6;
  unsigned short* LB = (unsigned short*)S;

#pragma unroll
  for (int hh = 0; hh < 2; ++hh) {
    __syncthreads();
    if (wn == hh) {
#pragma unroll
      for (int i = 0; i < 4; ++i) {
        const int rl = wm * 64 + i * 16 + g * 4;
#pragma unroll
        for (int jj = 0; jj < 4; ++jj) {
          const int col = jj * 16 + c;
#pragma unroll
          for (int r = 0; r < 4; ++r) {
            const int row = rl + r;
            __bf16 v = f2bf(acc[i][jj][r] + bb4[jj]);
            if (seg < 2) {
              LB[row * 72 + col] = __builtin_bit_cast(unsigned short, v);
            } else {
              int spl = (row & ~0x1C) | ((row & 0x0C) << 1) | ((row & 0x10) >> 2);
              LB[col * 136 + spl] = __builtin_bit_cast(unsigned short, v);
            }
          }
        }
      }
    }
    __syncthreads();
    if (seg < 2) {
      __bf16* dst = (__bf16*)(seg == 0 ? o0 : o1);
      const size_t hbase = ((size_t)(bidx * 16 + hb + hh) * 2048 + s0g) * 64;
#pragma unroll
      for (int s4 = 0; s4 < 4; ++s4) {
        int row = s4 * 32 + (t >> 3);
        int hd0 = (t & 7) * 8;
        bf16x8 v = *(const bf16x8*)&LB[row * 72 + hd0];
        *(bf16x8*)&dst[hbase + (size_t)row * 64 + hd0] = v;
      }
    } else {
      __bf16* dst = (__bf16*)o2;
      const int hd = t >> 2, q4 = t & 3;
      const size_t vb = ((size_t)(bidx * 16 + hb + hh) * 64 + hd) * 2048 + s0g;
#pragma unroll
      for (int kk = 0; kk < 4; ++kk) {
        int spb = q4 * 32 + kk * 8;
        bf16x8 v = *(const bf16x8*)&LB[hd * 136 + spb];
        *(bf16x8*)&dst[vb + spb] = v;
      }
    }
  }
}

// ------------------------------------------------------------ flash attention v7
// q,k: (BH,S,64) bf16 (q pre-scaled by 0.125*log2e); vt: (BH,64,S) bf16 SLOT-PERMUTED
// out: (B*S,1024) bf16. 4 waves, 32 q-rows/wave, KVBLK=64.
// K TRIPLE-buffered LDS (one barrier/iter); V fragments read DIRECT from global
// (L2-resident: heads XCD-pinned). vf0 issued at iter top (under counted vmcnt),
// vf1 issued after PV-h0 (register-pressure split).
__global__ __launch_bounds__(256, 4) void attn_kernel(const __bf16* __restrict__ q,
                                                      const __bf16* __restrict__ k,
                                                      const __bf16* __restrict__ vt,
                                                      const unsigned* __restrict__ pm,
                                                      __bf16* __restrict__ outp) {
  const int bid = blockIdx.x;
  const int xcd = bid & 7, j = bid >> 3;
  const int bh = xcd * 8 + (j & 7), qb = j >> 3;   // same-bh blocks share an XCD
  const int b = bh >> 4, h = bh & 15;
  const int t = threadIdx.x, lane = t & 63, w = t >> 6;
  const int g = lane >> 4, c = lane & 15;
  const int sw = c & 7;

  __shared__ alignas(16) __bf16 S[12288];   // K ring: 3 x 4096; epilogue reuse

  const size_t kbase = (size_t)bh * (2048 * 64);
  const size_t vbase = (size_t)bh * (64 * 2048);
  const int q0 = qb * 128 + w * 32;

  unsigned mword = pm[b * 64 + lane];

  bf16x8 qf[2][2];
#pragma unroll
  for (int i = 0; i < 2; ++i)
#pragma unroll
    for (int m = 0; m < 2; ++m)
      qf[i][m] = *(const bf16x8*)&q[kbase + (size_t)(q0 + i * 16 + c) * 64 + m * 32 + g * 8];
  asm volatile("" :: "v"(qf[0][0]), "v"(qf[0][1]), "v"(qf[1][0]), "v"(qf[1][1]),
                     "v"(mword) : "memory");

  f32x4 acc[2][4];
  f32x4 lacc[2];
#pragma unroll
  for (int i = 0; i < 2; ++i) {
    lacc[i] = f32x4{0.f, 0.f, 0.f, 0.f};
#pragma unroll
    for (int n = 0; n < 4; ++n) acc[i][n] = f32x4{0.f, 0.f, 0.f, 0.f};
  }

  const bf16x8 ones = { (__bf16)1.f, (__bf16)1.f, (__bf16)1.f, (__bf16)1.f,
                        (__bf16)1.f, (__bf16)1.f, (__bf16)1.f, (__bf16)1.f };

  auto stageK = [&](int buf, int kv0) {
#pragma unroll
    for (int r2 = 0; r2 < 2; ++r2) {
      int slot = r2 * 256 + t;
      int row = slot >> 3, ch = slot & 7;
      int gch = ch ^ (row & 7);
      gload16(&k[kbase + (size_t)(kv0 + row) * 64 + gch * 8], &S[buf * 4096 + slot * 8]);
    }
  };

  stageK(0, 0);   // 2 outstanding

#pragma unroll 1
  for (int kv = 0; kv < 32; ++kv) {
    const int kv0 = kv << 6;
    const __bf16* ksb = S + (kv % 3) * 4096;
    // V row base for this tile (slot-permuted global layout; swizzle cancels)
    const __bf16* vrow = &vt[vbase + kv0];

    if (kv < 31) stageK((kv + 1) % 3, kv0 + 64);   // +2 VMEM
    // vf0: chunks g (keys for PV half0) — issued now, counted below
    bf16x8 vf0[4];
#pragma unroll
    for (int n = 0; n < 4; ++n)
      vf0[n] = *(const bf16x8*)&vrow[(size_t)(n * 16 + c) * 2048 + g * 8];
    if (kv < 31) {
      asm volatile("s_waitcnt vmcnt(6)" ::: "memory");   // stageK(kv) landed
    } else {
      asm volatile("s_waitcnt vmcnt(4)" ::: "memory");
    }
    __builtin_amdgcn_s_barrier();                         // buf kv%3 visible

    unsigned mwlo = __builtin_amdgcn_readlane(mword, 2 * kv);
    unsigned mwhi = __builtin_amdgcn_readlane(mword, 2 * kv + 1);

    __builtin_amdgcn_s_setprio(1);
    f32x4 sc[2][4];
#pragma unroll
    for (int n = 0; n < 4; ++n) {
      bf16x8 kf0 = *(const bf16x8*)&ksb[(n * 16 + c) * 64 + (((0 + g) ^ sw) << 3)];
      bf16x8 kf1 = *(const bf16x8*)&ksb[(n * 16 + c) * 64 + (((4 + g) ^ sw) << 3)];
#pragma unroll
      for (int i = 0; i < 2; ++i) {
        f32x4 z = f32x4{0.f, 0.f, 0.f, 0.f};
        z = MFMA16(kf0, qf[i][0], z);
        z = MFMA16(kf1, qf[i][1], z);
        sc[i][n] = z;
      }
    }
    __builtin_amdgcn_sched_barrier(0);

    // ---- softmax half0 (keys 0..31) ----
    u32x4 pf0[2];
    if (mwlo) {
#pragma unroll
      for (int n = 0; n < 2; ++n)
#pragma unroll
        for (int r = 0; r < 4; ++r)
          if ((mwlo >> (n * 16 + g * 4 + r)) & 1u) { sc[0][n][r] = -1e30f; sc[1][n][r] = -1e30f; }
    }
#pragma unroll
    for (int i = 0; i < 2; ++i) {
      float p0 = EXP2(sc[i][0][0]), p1 = EXP2(sc[i][0][1]);
      float p2 = EXP2(sc[i][0][2]), p3 = EXP2(sc[i][0][3]);
      float p4 = EXP2(sc[i][1][0]), p5 = EXP2(sc[i][1][1]);
      float p6 = EXP2(sc[i][1][2]), p7 = EXP2(sc[i][1][3]);
      unsigned w0, w1, w2, w3;
      asm("v_cvt_pk_bf16_f32 %0, %1, %2" : "=v"(w0) : "v"(p0), "v"(p1));
      asm("v_cvt_pk_bf16_f32 %0, %1, %2" : "=v"(w1) : "v"(p2), "v"(p3));
      asm("v_cvt_pk_bf16_f32 %0, %1, %2" : "=v"(w2) : "v"(p4), "v"(p5));
      asm("v_cvt_pk_bf16_f32 %0, %1, %2" : "=v"(w3) : "v"(p6), "v"(p7));
      pf0[i] = u32x4{w0, w1, w2, w3};
    }

    // ---- PV half0 (vf0 from global; compiler inserts its own vmcnt) ----
#pragma unroll
    for (int n = 0; n < 4; ++n)
#pragma unroll
      for (int i = 0; i < 2; ++i)
        acc[i][n] = MFMA16(vf0[n], __builtin_bit_cast(bf16x8, pf0[i]), acc[i][n]);
#pragma unroll
    for (int i = 0; i < 2; ++i)
      lacc[i] = MFMA16(ones, __builtin_bit_cast(bf16x8, pf0[i]), lacc[i]);
    __builtin_amdgcn_sched_barrier(0);

    // vf1: chunks 4+g (keys for PV half1) — issue here so latency hides under SM-h1
    bf16x8 vf1[4];
#pragma unroll
    for (int n = 0; n < 4; ++n)
      vf1[n] = *(const bf16x8*)&vrow[(size_t)(n * 16 + c) * 2048 + (4 + g) * 8];
    __builtin_amdgcn_sched_barrier(0);

    // ---- softmax half1 (keys 32..63) ----
    u32x4 pf1[2];
    if (mwhi) {
#pragma unroll
      for (int n = 2; n < 4; ++n)
#pragma unroll
        for (int r = 0; r < 4; ++r)
          if ((mwhi >> ((n - 2) * 16 + g * 4 + r)) & 1u) { sc[0][n][r] = -1e30f; sc[1][n][r] = -1e30f; }
    }
#pragma unroll
    for (int i = 0; i < 2; ++i) {
      float p0 = EXP2(sc[i][2][0]), p1 = EXP2(sc[i][2][1]);
      float p2 = EXP2(sc[i][2][2]), p3 = EXP2(sc[i][2][3]);
      float p4 = EXP2(sc[i][3][0]), p5 = EXP2(sc[i][3][1]);
      float p6 = EXP2(sc[i][3][2]), p7 = EXP2(sc[i][3][3]);
      unsigned w0, w1, w2, w3;
      asm("v_cvt_pk_bf16_f32 %0, %1, %2" : "=v"(w0) : "v"(p0), "v"(p1));
      asm("v_cvt_pk_bf16_f32 %0, %1, %2" : "=v"(w1) : "v"(p2), "v"(p3));
      asm("v_cvt_pk_bf16_f32 %0, %1, %2" : "=v"(w2) : "v"(p4), "v"(p5));
      asm("v_cvt_pk_bf16_f32 %0, %1, %2" : "=v"(w3) : "v"(p6), "v"(p7));
      pf1[i] = u32x4{w0, w1, w2, w3};
    }

    // ---- PV half1 ----
#pragma unroll
    for (int n = 0; n < 4; ++n)
#pragma unroll
      for (int i = 0; i < 2; ++i)
        acc[i][n] = MFMA16(vf1[n], __builtin_bit_cast(bf16x8, pf1[i]), acc[i][n]);
#pragma unroll
    for (int i = 0; i < 2; ++i)
      lacc[i] = MFMA16(ones, __builtin_bit_cast(bf16x8, pf1[i]), lacc[i]);
    __builtin_amdgcn_s_setprio(0);
    // no end-of-iter barrier: K triple-buffer tolerates 1-iter wave skew
  }

  __syncthreads();   // all waves done with K ring before S is reused

  float linv[2];
#pragma unroll
  for (int i = 0; i < 2; ++i) linv[i] = 1.0f / fmaxf(lacc[i][0], 1e-30f);

  __bf16* ot = S + w * 2176;   // 32 rows x stride 68 per wave
#pragma unroll
  for (int i = 0; i < 2; ++i)
#pragma unroll
    for (int n = 0; n < 4; ++n) {
      float a0 = acc[i][n][0] * linv[i], a1 = acc[i][n][1] * linv[i];
      float a2 = acc[i][n][2] * linv[i], a3 = acc[i][n][3] * linv[i];
      unsigned w0, w1;
      asm("v_cvt_pk_bf16_f32 %0, %1, %2" : "=v"(w0) : "v"(a0), "v"(a1));
      asm("v_cvt_pk_bf16_f32 %0, %1, %2" : "=v"(w1) : "v"(a2), "v"(a3));
      *(u32x2*)&ot[(i * 16 + c) * 68 + n * 16 + g * 4] = u32x2{w0, w1};
    }
  asm volatile("s_waitcnt lgkmcnt(0)" ::: "memory");
  __builtin_amdgcn_sched_barrier(0);
#pragma unroll
  for (int ps = 0; ps < 4; ++ps) {
    int rr = ps * 8 + (lane >> 3);
    bf16x8 ov = *(const bf16x8*)&ot[rr * 68 + (lane & 7) * 8];
    *(bf16x8*)&outp[((size_t)b * 2048 + q0 + rr) * 1024 + h * 64 + (lane & 7) * 8] = ov;
  }
}

// ----------------------------------------------------------------- launcher
extern "C" void kernel_launch(void* const* d_in, const int* in_sizes, int n_in,
                              void* d_out, int out_size, void* d_ws, size_t ws_size,
                              hipStream_t stream) {
  (void)in_sizes; (void)n_in; (void)out_size; (void)ws_size;
  const float* x  = (const float*)d_in[0];
  const unsigned char* mask = (const unsigned char*)d_in[1];
  const float* Wq = (const float*)d_in[2];
  const float* bq = (const float*)d_in[3];
  const float* Wk = (const float*)d_in[4];
  const float* bk = (const float*)d_in[5];
  const float* Wv = (const float*)d_in[6];
  const float* bv = (const float*)d_in[7];
  const float* Wo = (const float*)d_in[8];
  const float* bo = (const float*)d_in[9];
  float* out = (float*)d_out;

  char* ws = (char*)d_ws;
  const size_t SZ = (size_t)8192 * 1024 * 2;
  const size_t WSZ = (size_t)1024 * 1024 * 2;
  __bf16* xb  = (__bf16*)(ws);
  __bf16* qb  = (__bf16*)(ws + SZ);
  __bf16* kb  = (__bf16*)(ws + 2 * SZ);
  __bf16* vtb = (__bf16*)(ws + 3 * SZ);
  __bf16* wtq = (__bf16*)(ws + 4 * SZ);            // wtq,wtk,wtv,wto contiguous
  __bf16* wto = (__bf16*)(ws + 4 * SZ + 3 * WSZ);
  unsigned* pmask = (unsigned*)(ws + 4 * SZ + 4 * WSZ);
  float* pb = (float*)(ws + 4 * SZ + 4 * WSZ + 4096);

  const float QSCALE = 0.125f * 1.44269504f;

  // fused pre-pass: x->bf16, 4x W^T->bf16, mask pack, bias pack
  prep<<<dim3(6145), 256, 0, stream>>>(x, (bf16x4v*)xb, Wq, Wk, Wv, Wo, wtq, QSCALE,
                                       mask, pmask, bq, bk, bv, pb);
  // fused QKV projection (N=3072)
  gemm128<<<dim3(1536), 256, 0, stream>>>(xb, wtq, pb, qb, kb, vtb, 3);
  attn_kernel<<<dim3(1024), 256, 0, stream>>>(qb, kb, vtb, pmask, xb);
  // output projection (N=1024)
  gemm128<<<dim3(512), 256, 0, stream>>>(xb, wto, bo, out, nullptr, nullptr, 2);
}

// Round 11
// 170.523 us; speedup vs baseline: 1.4285x; 1.4285x over previous
//
#include <hip/hip_runtime.h>
#include <cstdint>

// MHA fwd: B=4, S=2048, D=1024, H=16, HD=64. fp32 in/out.
// Round 11: attn reverted to round-9 kernel (74 µs, issue-saturated: MfmaUtil 43.5
// + VALUBusy 45); GEMMs = m97 structure (round 9); pre-passes fused (round 10's
// prep, the only part of r10 that worked). V-direct experiment reverted: stride-4KB
// per-lane reads destroyed coalescing (64 lines/wave-load, MfmaUtil 43->19).

typedef __bf16 bf16x8 __attribute__((ext_vector_type(8)));
typedef __bf16 bf16x4v __attribute__((ext_vector_type(4)));
typedef float f32x4 __attribute__((ext_vector_type(4)));
typedef unsigned u32x2 __attribute__((ext_vector_type(2)));
typedef unsigned u32x4 __attribute__((ext_vector_type(4)));

#define DEV __device__ __forceinline__

#if __has_builtin(__builtin_amdgcn_exp2f)
#define EXP2(x) __builtin_amdgcn_exp2f(x)
#else
#define EXP2(x) exp2f(x)
#endif

DEV __bf16 f2bf(float f) { return (__bf16)f; }

DEV void gload16(const void* g, void* l) {
  __builtin_amdgcn_global_load_lds(
      (const __attribute__((address_space(1))) unsigned int*)(uintptr_t)g,
      (__attribute__((address_space(3))) unsigned int*)(uintptr_t)l,
      16, 0, 0);
}

#define MFMA16(a, b, c) __builtin_amdgcn_mfma_f32_16x16x32_bf16((a), (b), (c), 0, 0, 0)

// ------------------------------------------------------- fused pre-pass kernel
// blocks [0,2048): x fp32 -> bf16 (grid-stride float4)
// blocks [2048,6144): W transpose+convert: which = (blk-2048)>>10
// block 6144: mask bit-pack + qkv bias pack
__global__ __launch_bounds__(256) void prep(const float* __restrict__ x,
                                            bf16x4v* __restrict__ xb,
                                            const float* __restrict__ Wq,
                                            const float* __restrict__ Wk,
                                            const float* __restrict__ Wv,
                                            const float* __restrict__ Wo,
                                            __bf16* __restrict__ wtall, float qs,
                                            const unsigned char* __restrict__ mask,
                                            unsigned* __restrict__ pm,
                                            const float* __restrict__ bq,
                                            const float* __restrict__ bk,
                                            const float* __restrict__ bv,
                                            float* __restrict__ pb) {
  const int blk = blockIdx.x, t = threadIdx.x;
  if (blk < 2048) {
    const float4* in = (const float4*)x;
    int i = blk * 256 + t;
    for (; i < 2097152; i += 2048 * 256) {
      float4 v = in[i];
      bf16x4v o = { f2bf(v.x), f2bf(v.y), f2bf(v.z), f2bf(v.w) };
      xb[i] = o;
    }
  } else if (blk < 6144) {
    __shared__ float tile[32][33];
    const int idx = blk - 2048;
    const int which = idx >> 10, tb = idx & 1023;
    const float* src = which == 0 ? Wq : which == 1 ? Wk : which == 2 ? Wv : Wo;
    const float scale = (which == 0) ? qs : 1.0f;
    __bf16* dst = wtall + (size_t)which * 1024 * 1024;
    const int tx = t & 31, ty = t >> 5;
    const int x0 = (tb & 31) * 32, y0 = (tb >> 5) * 32;
#pragma unroll
    for (int j = 0; j < 4; ++j)
      tile[ty + j * 8][tx] = src[(size_t)(y0 + ty + j * 8) * 1024 + x0 + tx];
    __syncthreads();
#pragma unroll
    for (int j = 0; j < 4; ++j)
      dst[(size_t)(x0 + ty + j * 8) * 1024 + y0 + tx] = f2bf(tile[tx][ty + j * 8] * scale);
  } else {
    int b = t >> 6, tl = (t >> 1) & 31, half = t & 1;
    unsigned bits = 0;
    for (int j = 0; j < 32; ++j)
      if (mask[b * 2048 + tl * 64 + half * 32 + j]) bits |= (1u << j);
    pm[b * 64 + tl * 2 + half] = bits;
    for (int i = t; i < 3072; i += 256) {
      float v = (i < 1024) ? bq[i] * qs : (i < 2048) ? bk[i - 1024] : bv[i - 2048];
      pb[i] = v;
    }
  }
}

// --------------------------------------------------------------- 128x128 GEMM
// m97 structure: single-buffered 32KB LDS, stage -> __syncthreads -> MFMA ->
// __syncthreads; XOR chunk-swizzled staging/reads; 4 blocks/CU; m-fast XCD grid.
// mode 2: fp32 row-major out to o0 (N=1024)
// mode 3: fused QKV (N=3072): seg 0 -> q head-split, 1 -> k head-split,
//         2 -> v transposed (bh,hd,s) with in-tile key-slot permutation.
__global__ __launch_bounds__(256, 4) void gemm128(const __bf16* __restrict__ A,
                                                  const __bf16* __restrict__ Bt,
                                                  const float* __restrict__ bias,
                                                  void* __restrict__ o0, void* __restrict__ o1,
                                                  void* __restrict__ o2, int mode) {
  constexpr int K = 1024;
  __shared__ alignas(16) __bf16 S[16384];
  __bf16* As_ = S;
  __bf16* Bs_ = S + 8192;
  const int t = threadIdx.x;
  const int lane = t & 63, w = t >> 6;
  const int g = lane >> 4, c = lane & 15;
  const int sw = c & 7;
  const int wm = w & 1, wn = w >> 1;
  const int bid = blockIdx.x;
  const int j = bid >> 3;
  const int m0 = (((bid & 7) << 3) + (j & 7)) << 7;
  const int n0 = (j >> 3) << 7;

  float bb4[4];
#pragma unroll
  for (int jj = 0; jj < 4; ++jj) bb4[jj] = bias[n0 + wn * 64 + jj * 16 + c];

  f32x4 acc[4][4];
#pragma unroll
  for (int i = 0; i < 4; ++i)
#pragma unroll
    for (int jj = 0; jj < 4; ++jj) acc[i][jj] = f32x4{0.f, 0.f, 0.f, 0.f};

#pragma unroll 1
  for (int kt = 0; kt < 16; ++kt) {
    const int k0 = kt << 6;
#pragma unroll
    for (int i = 0; i < 4; ++i) {
      int slot = i * 256 + t;
      int row = slot >> 3;
      int gch = (slot & 7) ^ (row & 7);
      gload16(&A[(size_t)(m0 + row) * K + k0 + gch * 8], &As_[slot * 8]);
      gload16(&Bt[(size_t)(n0 + row) * K + k0 + gch * 8], &Bs_[slot * 8]);
    }
    __syncthreads();
#pragma unroll
    for (int kk = 0; kk < 2; ++kk) {
      bf16x8 af[4], bfr[4];
#pragma unroll
      for (int i = 0; i < 4; ++i) {
        af[i]  = *(const bf16x8*)&As_[(wm * 64 + i * 16 + c) * 64 + (((kk * 4 + g) ^ sw) << 3)];
        bfr[i] = *(const bf16x8*)&Bs_[(wn * 64 + i * 16 + c) * 64 + (((kk * 4 + g) ^ sw) << 3)];
      }
#pragma unroll
      for (int i = 0; i < 4; ++i)
#pragma unroll
        for (int jj = 0; jj < 4; ++jj)
          acc[i][jj] = MFMA16(af[i], bfr[jj], acc[i][jj]);
    }
    __syncthreads();
  }

  const int bidx = m0 >> 11;
  const int s0g = m0 & 2047;

  if (mode == 2) {
#pragma unroll
    for (int i = 0; i < 4; ++i) {
      const int rowb = m0 + wm * 64 + i * 16 + g * 4;
#pragma unroll
      for (int jj = 0; jj < 4; ++jj) {
        const int col = n0 + wn * 64 + jj * 16 + c;
#pragma unroll
        for (int r = 0; r < 4; ++r)
          ((float*)o0)[(size_t)(rowb + r) * 1024 + col] = acc[i][jj][r] + bb4[jj];
      }
    }
    return;
  }

  const int seg = n0 >> 10;
  const int hb = (n0 & 1023) >> 6;
  unsigned short* LB = (unsigned short*)S;

#pragma unroll
  for (int hh = 0; hh < 2; ++hh) {
    __syncthreads();
    if (wn == hh) {
#pragma unroll
      for (int i = 0; i < 4; ++i) {
        const int rl = wm * 64 + i * 16 + g * 4;
#pragma unroll
        for (int jj = 0; jj < 4; ++jj) {
          const int col = jj * 16 + c;
#pragma unroll
          for (int r = 0; r < 4; ++r) {
            const int row = rl + r;
            __bf16 v = f2bf(acc[i][jj][r] + bb4[jj]);
            if (seg < 2) {
              LB[row * 72 + col] = __builtin_bit_cast(unsigned short, v);
            } else {
              int spl = (row & ~0x1C) | ((row & 0x0C) << 1) | ((row & 0x10) >> 2);
              LB[col * 136 + spl] = __builtin_bit_cast(unsigned short, v);
            }
          }
        }
      }
    }
    __syncthreads();
    if (seg < 2) {
      __bf16* dst = (__bf16*)(seg == 0 ? o0 : o1);
      const size_t hbase = ((size_t)(bidx * 16 + hb + hh) * 2048 + s0g) * 64;
#pragma unroll
      for (int s4 = 0; s4 < 4; ++s4) {
        int row = s4 * 32 + (t >> 3);
        int hd0 = (t & 7) * 8;
        bf16x8 v = *(const bf16x8*)&LB[row * 72 + hd0];
        *(bf16x8*)&dst[hbase + (size_t)row * 64 + hd0] = v;
      }
    } else {
      __bf16* dst = (__bf16*)o2;
      const int hd = t >> 2, q4 = t & 3;
      const size_t vb = ((size_t)(bidx * 16 + hb + hh) * 64 + hd) * 2048 + s0g;
#pragma unroll
      for (int kk = 0; kk < 4; ++kk) {
        int spb = q4 * 32 + kk * 8;
        bf16x8 v = *(const bf16x8*)&LB[hd * 136 + spb];
        *(bf16x8*)&dst[vb + spb] = v;
      }
    }
  }
}

// ------------------------------------------------------------ flash attention v6 (round-9)
// q,k: (BH,S,64) bf16 (q pre-scaled by 0.125*log2e); vt: (BH,64,S) bf16 SLOT-PERMUTED
// out: (B*S,1024) bf16. 4 waves, 32 q-rows/wave, KVBLK=64. K dbuf + counted
// vmcnt(2), V staged post-barrier; swapped QK^T, P-in-registers, half-split softmax.
__global__ __launch_bounds__(256, 4) void attn_kernel(const __bf16* __restrict__ q,
                                                      const __bf16* __restrict__ k,
                                                      const __bf16* __restrict__ vt,
                                                      const unsigned* __restrict__ pm,
                                                      __bf16* __restrict__ outp) {
  const int bid = blockIdx.x;
  const int xcd = bid & 7, j = bid >> 3;
  const int bh = xcd * 8 + (j & 7), qb = j >> 3;
  const int b = bh >> 4, h = bh & 15;
  const int t = threadIdx.x, lane = t & 63, w = t >> 6;
  const int g = lane >> 4, c = lane & 15;
  const int sw = c & 7;

  __shared__ alignas(16) __bf16 S[12288];
  __bf16* Vs = S + 8192;

  const size_t kbase = (size_t)bh * (2048 * 64);
  const size_t vbase = (size_t)bh * (64 * 2048);
  const int q0 = qb * 128 + w * 32;

  unsigned mword = pm[b * 64 + lane];

  bf16x8 qf[2][2];
#pragma unroll
  for (int i = 0; i < 2; ++i)
#pragma unroll
    for (int m = 0; m < 2; ++m)
      qf[i][m] = *(const bf16x8*)&q[kbase + (size_t)(q0 + i * 16 + c) * 64 + m * 32 + g * 8];
  asm volatile("" :: "v"(qf[0][0]), "v"(qf[0][1]), "v"(qf[1][0]), "v"(qf[1][1]),
                     "v"(mword) : "memory");

  f32x4 acc[2][4];
  f32x4 lacc[2];
#pragma unroll
  for (int i = 0; i < 2; ++i) {
    lacc[i] = f32x4{0.f, 0.f, 0.f, 0.f};
#pragma unroll
    for (int n = 0; n < 4; ++n) acc[i][n] = f32x4{0.f, 0.f, 0.f, 0.f};
  }

  const bf16x8 ones = { (__bf16)1.f, (__bf16)1.f, (__bf16)1.f, (__bf16)1.f,
                        (__bf16)1.f, (__bf16)1.f, (__bf16)1.f, (__bf16)1.f };

  auto stageK = [&](int bb, int kv0) {
#pragma unroll
    for (int r2 = 0; r2 < 2; ++r2) {
      int slot = r2 * 256 + t;
      int row = slot >> 3, ch = slot & 7;
      int gch = ch ^ (row & 7);
      gload16(&k[kbase + (size_t)(kv0 + row) * 64 + gch * 8], &S[bb * 4096 + slot * 8]);
    }
  };
  auto stageV = [&](int kv0) {
#pragma unroll
    for (int r2 = 0; r2 < 2; ++r2) {
      int slot = r2 * 256 + t;
      int row = slot >> 3, ch = slot & 7;
      int gch = ch ^ (row & 7);
      gload16(&vt[vbase + (size_t)row * 2048 + kv0 + gch * 8], &Vs[slot * 8]);
    }
  };

  stageK(0, 0);
  stageV(0);

#pragma unroll 1
  for (int kv = 0; kv < 32; ++kv) {
    const int bb = kv & 1;
    const int kv0 = kv << 6;
    if (kv < 31) {
      stageK(bb ^ 1, kv0 + 64);
      asm volatile("s_waitcnt vmcnt(2)" ::: "memory");
    } else {
      asm volatile("s_waitcnt vmcnt(0)" ::: "memory");
    }
    __builtin_amdgcn_s_barrier();

    const __bf16* ksb = S + (bb << 12);
    unsigned mwlo = __builtin_amdgcn_readlane(mword, 2 * kv);
    unsigned mwhi = __builtin_amdgcn_readlane(mword, 2 * kv + 1);

    __builtin_amdgcn_s_setprio(1);
    f32x4 sc[2][4];
#pragma unroll
    for (int n = 0; n < 4; ++n) {
      bf16x8 kf0 = *(const bf16x8*)&ksb[(n * 16 + c) * 64 + (((0 + g) ^ sw) << 3)];
      bf16x8 kf1 = *(const bf16x8*)&ksb[(n * 16 + c) * 64 + (((4 + g) ^ sw) << 3)];
#pragma unroll
      for (int i = 0; i < 2; ++i) {
        f32x4 z = f32x4{0.f, 0.f, 0.f, 0.f};
        z = MFMA16(kf0, qf[i][0], z);
        z = MFMA16(kf1, qf[i][1], z);
        sc[i][n] = z;
      }
    }
    __builtin_amdgcn_sched_barrier(0);

    u32x4 pf0[2];
    if (mwlo) {
#pragma unroll
      for (int n = 0; n < 2; ++n)
#pragma unroll
        for (int r = 0; r < 4; ++r)
          if ((mwlo >> (n * 16 + g * 4 + r)) & 1u) { sc[0][n][r] = -1e30f; sc[1][n][r] = -1e30f; }
    }
#pragma unroll
    for (int i = 0; i < 2; ++i) {
      float p0 = EXP2(sc[i][0][0]), p1 = EXP2(sc[i][0][1]);
      float p2 = EXP2(sc[i][0][2]), p3 = EXP2(sc[i][0][3]);
      float p4 = EXP2(sc[i][1][0]), p5 = EXP2(sc[i][1][1]);
      float p6 = EXP2(sc[i][1][2]), p7 = EXP2(sc[i][1][3]);
      unsigned w0, w1, w2, w3;
      asm("v_cvt_pk_bf16_f32 %0, %1, %2" : "=v"(w0) : "v"(p0), "v"(p1));
      asm("v_cvt_pk_bf16_f32 %0, %1, %2" : "=v"(w1) : "v"(p2), "v"(p3));
      asm("v_cvt_pk_bf16_f32 %0, %1, %2" : "=v"(w2) : "v"(p4), "v"(p5));
      asm("v_cvt_pk_bf16_f32 %0, %1, %2" : "=v"(w3) : "v"(p6), "v"(p7));
      pf0[i] = u32x4{w0, w1, w2, w3};
    }

#pragma unroll
    for (int n = 0; n < 4; ++n) {
      bf16x8 vf0 = *(const bf16x8*)&Vs[(n * 16 + c) * 64 + (((0 + g) ^ sw) << 3)];
#pragma unroll
      for (int i = 0; i < 2; ++i)
        acc[i][n] = MFMA16(vf0, __builtin_bit_cast(bf16x8, pf0[i]), acc[i][n]);
    }
#pragma unroll
    for (int i = 0; i < 2; ++i)
      lacc[i] = MFMA16(ones, __builtin_bit_cast(bf16x8, pf0[i]), lacc[i]);
    __builtin_amdgcn_sched_barrier(0);

    u32x4 pf1[2];
    if (mwhi) {
#pragma unroll
      for (int n = 2; n < 4; ++n)
#pragma unroll
        for (int r = 0; r < 4; ++r)
          if ((mwhi >> ((n - 2) * 16 + g * 4 + r)) & 1u) { sc[0][n][r] = -1e30f; sc[1][n][r] = -1e30f; }
    }
#pragma unroll
    for (int i = 0; i < 2; ++i) {
      float p0 = EXP2(sc[i][2][0]), p1 = EXP2(sc[i][2][1]);
      float p2 = EXP2(sc[i][2][2]), p3 = EXP2(sc[i][2][3]);
      float p4 = EXP2(sc[i][3][0]), p5 = EXP2(sc[i][3][1]);
      float p6 = EXP2(sc[i][3][2]), p7 = EXP2(sc[i][3][3]);
      unsigned w0, w1, w2, w3;
      asm("v_cvt_pk_bf16_f32 %0, %1, %2" : "=v"(w0) : "v"(p0), "v"(p1));
      asm("v_cvt_pk_bf16_f32 %0, %1, %2" : "=v"(w1) : "v"(p2), "v"(p3));
      asm("v_cvt_pk_bf16_f32 %0, %1, %2" : "=v"(w2) : "v"(p4), "v"(p5));
      asm("v_cvt_pk_bf16_f32 %0, %1, %2" : "=v"(w3) : "v"(p6), "v"(p7));
      pf1[i] = u32x4{w0, w1, w2, w3};
    }

#pragma unroll
    for (int n = 0; n < 4; ++n) {
      bf16x8 vf1 = *(const bf16x8*)&Vs[(n * 16 + c) * 64 + (((4 + g) ^ sw) << 3)];
#pragma unroll
      for (int i = 0; i < 2; ++i)
        acc[i][n] = MFMA16(vf1, __builtin_bit_cast(bf16x8, pf1[i]), acc[i][n]);
    }
#pragma unroll
    for (int i = 0; i < 2; ++i)
      lacc[i] = MFMA16(ones, __builtin_bit_cast(bf16x8, pf1[i]), lacc[i]);
    __builtin_amdgcn_s_setprio(0);

    __builtin_amdgcn_s_barrier();
    if (kv < 31) stageV(kv0 + 64);
  }

  float linv[2];
#pragma unroll
  for (int i = 0; i < 2; ++i) linv[i] = 1.0f / fmaxf(lacc[i][0], 1e-30f);

  __bf16* ot = S + w * 2176;
#pragma unroll
  for (int i = 0; i < 2; ++i)
#pragma unroll
    for (int n = 0; n < 4; ++n) {
      float a0 = acc[i][n][0] * linv[i], a1 = acc[i][n][1] * linv[i];
      float a2 = acc[i][n][2] * linv[i], a3 = acc[i][n][3] * linv[i];
      unsigned w0, w1;
      asm("v_cvt_pk_bf16_f32 %0, %1, %2" : "=v"(w0) : "v"(a0), "v"(a1));
      asm("v_cvt_pk_bf16_f32 %0, %1, %2" : "=v"(w1) : "v"(a2), "v"(a3));
      *(u32x2*)&ot[(i * 16 + c) * 68 + n * 16 + g * 4] = u32x2{w0, w1};
    }
  asm volatile("s_waitcnt lgkmcnt(0)" ::: "memory");
  __builtin_amdgcn_sched_barrier(0);
#pragma unroll
  for (int ps = 0; ps < 4; ++ps) {
    int rr = ps * 8 + (lane >> 3);
    bf16x8 ov = *(const bf16x8*)&ot[rr * 68 + (lane & 7) * 8];
    *(bf16x8*)&outp[((size_t)b * 2048 + q0 + rr) * 1024 + h * 64 + (lane & 7) * 8] = ov;
  }
}

// ----------------------------------------------------------------- launcher
extern "C" void kernel_launch(void* const* d_in, const int* in_sizes, int n_in,
                              void* d_out, int out_size, void* d_ws, size_t ws_size,
                              hipStream_t stream) {
  (void)in_sizes; (void)n_in; (void)out_size; (void)ws_size;
  const float* x  = (const float*)d_in[0];
  const unsigned char* mask = (const unsigned char*)d_in[1];
  const float* Wq = (const float*)d_in[2];
  const float* bq = (const float*)d_in[3];
  const float* Wk = (const float*)d_in[4];
  const float* bk = (const float*)d_in[5];
  const float* Wv = (const float*)d_in[6];
  const float* bv = (const float*)d_in[7];
  const float* Wo = (const float*)d_in[8];
  const float* bo = (const float*)d_in[9];
  float* out = (float*)d_out;

  char* ws = (char*)d_ws;
  const size_t SZ = (size_t)8192 * 1024 * 2;
  const size_t WSZ = (size_t)1024 * 1024 * 2;
  __bf16* xb  = (__bf16*)(ws);
  __bf16* qb  = (__bf16*)(ws + SZ);
  __bf16* kb  = (__bf16*)(ws + 2 * SZ);
  __bf16* vtb = (__bf16*)(ws + 3 * SZ);
  __bf16* wtq = (__bf16*)(ws + 4 * SZ);            // wtq,wtk,wtv,wto contiguous
  __bf16* wto = (__bf16*)(ws + 4 * SZ + 3 * WSZ);
  unsigned* pmask = (unsigned*)(ws + 4 * SZ + 4 * WSZ);
  float* pb = (float*)(ws + 4 * SZ + 4 * WSZ + 4096);

  const float QSCALE = 0.125f * 1.44269504f;

  // fused pre-pass: x->bf16, 4x W^T->bf16, mask pack, bias pack
  prep<<<dim3(6145), 256, 0, stream>>>(x, (bf16x4v*)xb, Wq, Wk, Wv, Wo, wtq, QSCALE,
                                       mask, pmask, bq, bk, bv, pb);
  // fused QKV projection (N=3072)
  gemm128<<<dim3(1536), 256, 0, stream>>>(xb, wtq, pb, qb, kb, vtb, 3);
  attn_kernel<<<dim3(1024), 256, 0, stream>>>(qb, kb, vtb, pmask, xb);
  // output projection (N=1024)
  gemm128<<<dim3(512), 256, 0, stream>>>(xb, wto, bo, out, nullptr, nullptr, 2);
}

// Round 12
// 168.501 us; speedup vs baseline: 1.4456x; 1.0120x over previous
//
#include <hip/hip_runtime.h>
#include <cstdint>

// MHA fwd: B=4, S=2048, D=1024, H=16, HD=64. fp32 in/out.
// Round 12: attn v8 = round-9 math, 8-wave blocks (512 thr, qblock 256):
// per-thread staging halves (1 gload16 for K + 1 for V per iter), K/V fetch
// halves, per-wave math/registers unchanged. vmcnt re-derived: in-loop wait
// vmcnt(1). GEMMs = m97 structure; prep fused (round 11).

typedef __bf16 bf16x8 __attribute__((ext_vector_type(8)));
typedef __bf16 bf16x4v __attribute__((ext_vector_type(4)));
typedef float f32x4 __attribute__((ext_vector_type(4)));
typedef unsigned u32x2 __attribute__((ext_vector_type(2)));
typedef unsigned u32x4 __attribute__((ext_vector_type(4)));

#define DEV __device__ __forceinline__

#if __has_builtin(__builtin_amdgcn_exp2f)
#define EXP2(x) __builtin_amdgcn_exp2f(x)
#else
#define EXP2(x) exp2f(x)
#endif

DEV __bf16 f2bf(float f) { return (__bf16)f; }

DEV void gload16(const void* g, void* l) {
  __builtin_amdgcn_global_load_lds(
      (const __attribute__((address_space(1))) unsigned int*)(uintptr_t)g,
      (__attribute__((address_space(3))) unsigned int*)(uintptr_t)l,
      16, 0, 0);
}

#define MFMA16(a, b, c) __builtin_amdgcn_mfma_f32_16x16x32_bf16((a), (b), (c), 0, 0, 0)

// ------------------------------------------------------- fused pre-pass kernel
// blocks [0,2048): x fp32 -> bf16 (grid-stride float4)
// blocks [2048,6144): W transpose+convert: which = (blk-2048)>>10
// block 6144: mask bit-pack + qkv bias pack
__global__ __launch_bounds__(256) void prep(const float* __restrict__ x,
                                            bf16x4v* __restrict__ xb,
                                            const float* __restrict__ Wq,
                                            const float* __restrict__ Wk,
                                            const float* __restrict__ Wv,
                                            const float* __restrict__ Wo,
                                            __bf16* __restrict__ wtall, float qs,
                                            const unsigned char* __restrict__ mask,
                                            unsigned* __restrict__ pm,
                                            const float* __restrict__ bq,
                                            const float* __restrict__ bk,
                                            const float* __restrict__ bv,
                                            float* __restrict__ pb) {
  const int blk = blockIdx.x, t = threadIdx.x;
  if (blk < 2048) {
    const float4* in = (const float4*)x;
    int i = blk * 256 + t;
    for (; i < 2097152; i += 2048 * 256) {
      float4 v = in[i];
      bf16x4v o = { f2bf(v.x), f2bf(v.y), f2bf(v.z), f2bf(v.w) };
      xb[i] = o;
    }
  } else if (blk < 6144) {
    __shared__ float tile[32][33];
    const int idx = blk - 2048;
    const int which = idx >> 10, tb = idx & 1023;
    const float* src = which == 0 ? Wq : which == 1 ? Wk : which == 2 ? Wv : Wo;
    const float scale = (which == 0) ? qs : 1.0f;
    __bf16* dst = wtall + (size_t)which * 1024 * 1024;
    const int tx = t & 31, ty = t >> 5;
    const int x0 = (tb & 31) * 32, y0 = (tb >> 5) * 32;
#pragma unroll
    for (int j = 0; j < 4; ++j)
      tile[ty + j * 8][tx] = src[(size_t)(y0 + ty + j * 8) * 1024 + x0 + tx];
    __syncthreads();
#pragma unroll
    for (int j = 0; j < 4; ++j)
      dst[(size_t)(x0 + ty + j * 8) * 1024 + y0 + tx] = f2bf(tile[tx][ty + j * 8] * scale);
  } else {
    int b = t >> 6, tl = (t >> 1) & 31, half = t & 1;
    unsigned bits = 0;
    for (int j = 0; j < 32; ++j)
      if (mask[b * 2048 + tl * 64 + half * 32 + j]) bits |= (1u << j);
    pm[b * 64 + tl * 2 + half] = bits;
    for (int i = t; i < 3072; i += 256) {
      float v = (i < 1024) ? bq[i] * qs : (i < 2048) ? bk[i - 1024] : bv[i - 2048];
      pb[i] = v;
    }
  }
}

// --------------------------------------------------------------- 128x128 GEMM
// m97 structure: single-buffered 32KB LDS, stage -> __syncthreads -> MFMA ->
// __syncthreads; XOR chunk-swizzled staging/reads; 4 blocks/CU; m-fast XCD grid.
// mode 2: fp32 row-major out to o0 (N=1024)
// mode 3: fused QKV (N=3072): seg 0 -> q head-split, 1 -> k head-split,
//         2 -> v transposed (bh,hd,s) with in-tile key-slot permutation.
__global__ __launch_bounds__(256, 4) void gemm128(const __bf16* __restrict__ A,
                                                  const __bf16* __restrict__ Bt,
                                                  const float* __restrict__ bias,
                                                  void* __restrict__ o0, void* __restrict__ o1,
                                                  void* __restrict__ o2, int mode) {
  constexpr int K = 1024;
  __shared__ alignas(16) __bf16 S[16384];
  __bf16* As_ = S;
  __bf16* Bs_ = S + 8192;
  const int t = threadIdx.x;
  const int lane = t & 63, w = t >> 6;
  const int g = lane >> 4, c = lane & 15;
  const int sw = c & 7;
  const int wm = w & 1, wn = w >> 1;
  const int bid = blockIdx.x;
  const int j = bid >> 3;
  const int m0 = (((bid & 7) << 3) + (j & 7)) << 7;
  const int n0 = (j >> 3) << 7;

  float bb4[4];
#pragma unroll
  for (int jj = 0; jj < 4; ++jj) bb4[jj] = bias[n0 + wn * 64 + jj * 16 + c];

  f32x4 acc[4][4];
#pragma unroll
  for (int i = 0; i < 4; ++i)
#pragma unroll
    for (int jj = 0; jj < 4; ++jj) acc[i][jj] = f32x4{0.f, 0.f, 0.f, 0.f};

#pragma unroll 1
  for (int kt = 0; kt < 16; ++kt) {
    const int k0 = kt << 6;
#pragma unroll
    for (int i = 0; i < 4; ++i) {
      int slot = i * 256 + t;
      int row = slot >> 3;
      int gch = (slot & 7) ^ (row & 7);
      gload16(&A[(size_t)(m0 + row) * K + k0 + gch * 8], &As_[slot * 8]);
      gload16(&Bt[(size_t)(n0 + row) * K + k0 + gch * 8], &Bs_[slot * 8]);
    }
    __syncthreads();
#pragma unroll
    for (int kk = 0; kk < 2; ++kk) {
      bf16x8 af[4], bfr[4];
#pragma unroll
      for (int i = 0; i < 4; ++i) {
        af[i]  = *(const bf16x8*)&As_[(wm * 64 + i * 16 + c) * 64 + (((kk * 4 + g) ^ sw) << 3)];
        bfr[i] = *(const bf16x8*)&Bs_[(wn * 64 + i * 16 + c) * 64 + (((kk * 4 + g) ^ sw) << 3)];
      }
#pragma unroll
      for (int i = 0; i < 4; ++i)
#pragma unroll
        for (int jj = 0; jj < 4; ++jj)
          acc[i][jj] = MFMA16(af[i], bfr[jj], acc[i][jj]);
    }
    __syncthreads();
  }

  const int bidx = m0 >> 11;
  const int s0g = m0 & 2047;

  if (mode == 2) {
#pragma unroll
    for (int i = 0; i < 4; ++i) {
      const int rowb = m0 + wm * 64 + i * 16 + g * 4;
#pragma unroll
      for (int jj = 0; jj < 4; ++jj) {
        const int col = n0 + wn * 64 + jj * 16 + c;
#pragma unroll
        for (int r = 0; r < 4; ++r)
          ((float*)o0)[(size_t)(rowb + r) * 1024 + col] = acc[i][jj][r] + bb4[jj];
      }
    }
    return;
  }

  const int seg = n0 >> 10;
  const int hb = (n0 & 1023) >> 6;
  unsigned short* LB = (unsigned short*)S;

#pragma unroll
  for (int hh = 0; hh < 2; ++hh) {
    __syncthreads();
    if (wn == hh) {
#pragma unroll
      for (int i = 0; i < 4; ++i) {
        const int rl = wm * 64 + i * 16 + g * 4;
#pragma unroll
        for (int jj = 0; jj < 4; ++jj) {
          const int col = jj * 16 + c;
#pragma unroll
          for (int r = 0; r < 4; ++r) {
            const int row = rl + r;
            __bf16 v = f2bf(acc[i][jj][r] + bb4[jj]);
            if (seg < 2) {
              LB[row * 72 + col] = __builtin_bit_cast(unsigned short, v);
            } else {
              int spl = (row & ~0x1C) | ((row & 0x0C) << 1) | ((row & 0x10) >> 2);
              LB[col * 136 + spl] = __builtin_bit_cast(unsigned short, v);
            }
          }
        }
      }
    }
    __syncthreads();
    if (seg < 2) {
      __bf16* dst = (__bf16*)(seg == 0 ? o0 : o1);
      const size_t hbase = ((size_t)(bidx * 16 + hb + hh) * 2048 + s0g) * 64;
#pragma unroll
      for (int s4 = 0; s4 < 4; ++s4) {
        int row = s4 * 32 + (t >> 3);
        int hd0 = (t & 7) * 8;
        bf16x8 v = *(const bf16x8*)&LB[row * 72 + hd0];
        *(bf16x8*)&dst[hbase + (size_t)row * 64 + hd0] = v;
      }
    } else {
      __bf16* dst = (__bf16*)o2;
      const int hd = t >> 2, q4 = t & 3;
      const size_t vb = ((size_t)(bidx * 16 + hb + hh) * 64 + hd) * 2048 + s0g;
#pragma unroll
      for (int kk = 0; kk < 4; ++kk) {
        int spb = q4 * 32 + kk * 8;
        bf16x8 v = *(const bf16x8*)&LB[hd * 136 + spb];
        *(bf16x8*)&dst[vb + spb] = v;
      }
    }
  }
}

// ------------------------------------------------------------ flash attention v8
// q,k: (BH,S,64) bf16 (q pre-scaled by 0.125*log2e); vt: (BH,64,S) bf16 SLOT-PERMUTED
// out: (B*S,1024) bf16. 8 waves (512 thr), 32 q-rows/wave (qblock 256), KVBLK=64.
// Per-thread staging: 1 gload16 K + 1 gload16 V per iter. K dbuf, counted vmcnt(1),
// V staged post-barrier. Swapped QK^T, P-in-registers, half-split softmax,
// lsum via ones-MFMA, mask via readlane.
__global__ __launch_bounds__(512, 4) void attn_kernel(const __bf16* __restrict__ q,
                                                      const __bf16* __restrict__ k,
                                                      const __bf16* __restrict__ vt,
                                                      const unsigned* __restrict__ pm,
                                                      __bf16* __restrict__ outp) {
  const int bid = blockIdx.x;
  const int xcd = bid & 7, j = bid >> 3;
  const int bh = xcd * 8 + (j & 7), qb = j >> 3;   // same-bh blocks share an XCD
  const int b = bh >> 4, h = bh & 15;
  const int t = threadIdx.x, lane = t & 63, w = t >> 6;   // w in 0..7
  const int g = lane >> 4, c = lane & 15;
  const int sw = c & 7;

  __shared__ alignas(16) __bf16 S[17408];   // Ks[2][4096] | Vs[4096]; epi 8x2176
  __bf16* Vs = S + 8192;

  const size_t kbase = (size_t)bh * (2048 * 64);
  const size_t vbase = (size_t)bh * (64 * 2048);
  const int q0 = qb * 256 + w * 32;

  unsigned mword = pm[b * 64 + lane];

  bf16x8 qf[2][2];
#pragma unroll
  for (int i = 0; i < 2; ++i)
#pragma unroll
    for (int m = 0; m < 2; ++m)
      qf[i][m] = *(const bf16x8*)&q[kbase + (size_t)(q0 + i * 16 + c) * 64 + m * 32 + g * 8];
  asm volatile("" :: "v"(qf[0][0]), "v"(qf[0][1]), "v"(qf[1][0]), "v"(qf[1][1]),
                     "v"(mword) : "memory");

  f32x4 acc[2][4];
  f32x4 lacc[2];
#pragma unroll
  for (int i = 0; i < 2; ++i) {
    lacc[i] = f32x4{0.f, 0.f, 0.f, 0.f};
#pragma unroll
    for (int n = 0; n < 4; ++n) acc[i][n] = f32x4{0.f, 0.f, 0.f, 0.f};
  }

  const bf16x8 ones = { (__bf16)1.f, (__bf16)1.f, (__bf16)1.f, (__bf16)1.f,
                        (__bf16)1.f, (__bf16)1.f, (__bf16)1.f, (__bf16)1.f };

  // 512 threads cover a 64x64 bf16 tile (512 slots) with ONE gload16 each
  auto stageK = [&](int bb, int kv0) {
    int row = t >> 3, ch = t & 7;
    int gch = ch ^ (row & 7);
    gload16(&k[kbase + (size_t)(kv0 + row) * 64 + gch * 8], &S[bb * 4096 + t * 8]);
  };
  auto stageV = [&](int kv0) {
    int row = t >> 3, ch = t & 7;
    int gch = ch ^ (row & 7);
    gload16(&vt[vbase + (size_t)row * 2048 + kv0 + gch * 8], &Vs[t * 8]);
  };

  stageK(0, 0);   // 1 outstanding
  stageV(0);      // +1

#pragma unroll 1
  for (int kv = 0; kv < 32; ++kv) {
    const int bb = kv & 1;
    const int kv0 = kv << 6;
    if (kv < 31) {
      stageK(bb ^ 1, kv0 + 64);                          // +1 in flight
      asm volatile("s_waitcnt vmcnt(1)" ::: "memory");   // K(kv),V(kv) landed
    } else {
      asm volatile("s_waitcnt vmcnt(0)" ::: "memory");
    }
    __builtin_amdgcn_s_barrier();

    const __bf16* ksb = S + (bb << 12);
    unsigned mwlo = __builtin_amdgcn_readlane(mword, 2 * kv);
    unsigned mwhi = __builtin_amdgcn_readlane(mword, 2 * kv + 1);

    __builtin_amdgcn_s_setprio(1);
    f32x4 sc[2][4];
#pragma unroll
    for (int n = 0; n < 4; ++n) {
      bf16x8 kf0 = *(const bf16x8*)&ksb[(n * 16 + c) * 64 + (((0 + g) ^ sw) << 3)];
      bf16x8 kf1 = *(const bf16x8*)&ksb[(n * 16 + c) * 64 + (((4 + g) ^ sw) << 3)];
#pragma unroll
      for (int i = 0; i < 2; ++i) {
        f32x4 z = f32x4{0.f, 0.f, 0.f, 0.f};
        z = MFMA16(kf0, qf[i][0], z);
        z = MFMA16(kf1, qf[i][1], z);
        sc[i][n] = z;
      }
    }
    __builtin_amdgcn_sched_barrier(0);

    u32x4 pf0[2];
    if (mwlo) {
#pragma unroll
      for (int n = 0; n < 2; ++n)
#pragma unroll
        for (int r = 0; r < 4; ++r)
          if ((mwlo >> (n * 16 + g * 4 + r)) & 1u) { sc[0][n][r] = -1e30f; sc[1][n][r] = -1e30f; }
    }
#pragma unroll
    for (int i = 0; i < 2; ++i) {
      float p0 = EXP2(sc[i][0][0]), p1 = EXP2(sc[i][0][1]);
      float p2 = EXP2(sc[i][0][2]), p3 = EXP2(sc[i][0][3]);
      float p4 = EXP2(sc[i][1][0]), p5 = EXP2(sc[i][1][1]);
      float p6 = EXP2(sc[i][1][2]), p7 = EXP2(sc[i][1][3]);
      unsigned w0, w1, w2, w3;
      asm("v_cvt_pk_bf16_f32 %0, %1, %2" : "=v"(w0) : "v"(p0), "v"(p1));
      asm("v_cvt_pk_bf16_f32 %0, %1, %2" : "=v"(w1) : "v"(p2), "v"(p3));
      asm("v_cvt_pk_bf16_f32 %0, %1, %2" : "=v"(w2) : "v"(p4), "v"(p5));
      asm("v_cvt_pk_bf16_f32 %0, %1, %2" : "=v"(w3) : "v"(p6), "v"(p7));
      pf0[i] = u32x4{w0, w1, w2, w3};
    }

#pragma unroll
    for (int n = 0; n < 4; ++n) {
      bf16x8 vf0 = *(const bf16x8*)&Vs[(n * 16 + c) * 64 + (((0 + g) ^ sw) << 3)];
#pragma unroll
      for (int i = 0; i < 2; ++i)
        acc[i][n] = MFMA16(vf0, __builtin_bit_cast(bf16x8, pf0[i]), acc[i][n]);
    }
#pragma unroll
    for (int i = 0; i < 2; ++i)
      lacc[i] = MFMA16(ones, __builtin_bit_cast(bf16x8, pf0[i]), lacc[i]);
    __builtin_amdgcn_sched_barrier(0);

    u32x4 pf1[2];
    if (mwhi) {
#pragma unroll
      for (int n = 2; n < 4; ++n)
#pragma unroll
        for (int r = 0; r < 4; ++r)
          if ((mwhi >> ((n - 2) * 16 + g * 4 + r)) & 1u) { sc[0][n][r] = -1e30f; sc[1][n][r] = -1e30f; }
    }
#pragma unroll
    for (int i = 0; i < 2; ++i) {
      float p0 = EXP2(sc[i][2][0]), p1 = EXP2(sc[i][2][1]);
      float p2 = EXP2(sc[i][2][2]), p3 = EXP2(sc[i][2][3]);
      float p4 = EXP2(sc[i][3][0]), p5 = EXP2(sc[i][3][1]);
      float p6 = EXP2(sc[i][3][2]), p7 = EXP2(sc[i][3][3]);
      unsigned w0, w1, w2, w3;
      asm("v_cvt_pk_bf16_f32 %0, %1, %2" : "=v"(w0) : "v"(p0), "v"(p1));
      asm("v_cvt_pk_bf16_f32 %0, %1, %2" : "=v"(w1) : "v"(p2), "v"(p3));
      asm("v_cvt_pk_bf16_f32 %0, %1, %2" : "=v"(w2) : "v"(p4), "v"(p5));
      asm("v_cvt_pk_bf16_f32 %0, %1, %2" : "=v"(w3) : "v"(p6), "v"(p7));
      pf1[i] = u32x4{w0, w1, w2, w3};
    }

#pragma unroll
    for (int n = 0; n < 4; ++n) {
      bf16x8 vf1 = *(const bf16x8*)&Vs[(n * 16 + c) * 64 + (((4 + g) ^ sw) << 3)];
#pragma unroll
      for (int i = 0; i < 2; ++i)
        acc[i][n] = MFMA16(vf1, __builtin_bit_cast(bf16x8, pf1[i]), acc[i][n]);
    }
#pragma unroll
    for (int i = 0; i < 2; ++i)
      lacc[i] = MFMA16(ones, __builtin_bit_cast(bf16x8, pf1[i]), lacc[i]);
    __builtin_amdgcn_s_setprio(0);

    __builtin_amdgcn_s_barrier();    // all waves done reading Ks[bb], Vs
    if (kv < 31) stageV(kv0 + 64);   // +1 outstanding
  }

  float linv[2];
#pragma unroll
  for (int i = 0; i < 2; ++i) linv[i] = 1.0f / fmaxf(lacc[i][0], 1e-30f);

  __bf16* ot = S + w * 2176;   // 8 waves x (32 rows x stride 68) = 17408 elems
#pragma unroll
  for (int i = 0; i < 2; ++i)
#pragma unroll
    for (int n = 0; n < 4; ++n) {
      float a0 = acc[i][n][0] * linv[i], a1 = acc[i][n][1] * linv[i];
      float a2 = acc[i][n][2] * linv[i], a3 = acc[i][n][3] * linv[i];
      unsigned w0, w1;
      asm("v_cvt_pk_bf16_f32 %0, %1, %2" : "=v"(w0) : "v"(a0), "v"(a1));
      asm("v_cvt_pk_bf16_f32 %0, %1, %2" : "=v"(w1) : "v"(a2), "v"(a3));
      *(u32x2*)&ot[(i * 16 + c) * 68 + n * 16 + g * 4] = u32x2{w0, w1};
    }
  asm volatile("s_waitcnt lgkmcnt(0)" ::: "memory");
  __builtin_amdgcn_sched_barrier(0);
#pragma unroll
  for (int ps = 0; ps < 4; ++ps) {
    int rr = ps * 8 + (lane >> 3);
    bf16x8 ov = *(const bf16x8*)&ot[rr * 68 + (lane & 7) * 8];
    *(bf16x8*)&outp[((size_t)b * 2048 + q0 + rr) * 1024 + h * 64 + (lane & 7) * 8] = ov;
  }
}

// ----------------------------------------------------------------- launcher
extern "C" void kernel_launch(void* const* d_in, const int* in_sizes, int n_in,
                              void* d_out, int out_size, void* d_ws, size_t ws_size,
                              hipStream_t stream) {
  (void)in_sizes; (void)n_in; (void)out_size; (void)ws_size;
  const float* x  = (const float*)d_in[0];
  const unsigned char* mask = (const unsigned char*)d_in[1];
  const float* Wq = (const float*)d_in[2];
  const float* bq = (const float*)d_in[3];
  const float* Wk = (const float*)d_in[4];
  const float* bk = (const float*)d_in[5];
  const float* Wv = (const float*)d_in[6];
  const float* bv = (const float*)d_in[7];
  const float* Wo = (const float*)d_in[8];
  const float* bo = (const float*)d_in[9];
  float* out = (float*)d_out;

  char* ws = (char*)d_ws;
  const size_t SZ = (size_t)8192 * 1024 * 2;
  const size_t WSZ = (size_t)1024 * 1024 * 2;
  __bf16* xb  = (__bf16*)(ws);
  __bf16* qb  = (__bf16*)(ws + SZ);
  __bf16* kb  = (__bf16*)(ws + 2 * SZ);
  __bf16* vtb = (__bf16*)(ws + 3 * SZ);
  __bf16* wtq = (__bf16*)(ws + 4 * SZ);            // wtq,wtk,wtv,wto contiguous
  __bf16* wto = (__bf16*)(ws + 4 * SZ + 3 * WSZ);
  unsigned* pmask = (unsigned*)(ws + 4 * SZ + 4 * WSZ);
  float* pb = (float*)(ws + 4 * SZ + 4 * WSZ + 4096);

  const float QSCALE = 0.125f * 1.44269504f;

  // fused pre-pass: x->bf16, 4x W^T->bf16, mask pack, bias pack
  prep<<<dim3(6145), 256, 0, stream>>>(x, (bf16x4v*)xb, Wq, Wk, Wv, Wo, wtq, QSCALE,
                                       mask, pmask, bq, bk, bv, pb);
  // fused QKV projection (N=3072)
  gemm128<<<dim3(1536), 256, 0, stream>>>(xb, wtq, pb, qb, kb, vtb, 3);
  attn_kernel<<<dim3(512), 512, 0, stream>>>(qb, kb, vtb, pmask, xb);
  // output projection (N=1024)
  gemm128<<<dim3(512), 256, 0, stream>>>(xb, wto, bo, out, nullptr, nullptr, 2);
}